// Round 3
// baseline (211.360 us; speedup 1.0000x reference)
//
#include <hip/hip_runtime.h>
#include <hip/hip_bf16.h>
#include <math.h>

#define N_BINS 229
#define MODEL  128
#define OUTD   88
#define WSZ    30
#define WLEN   61
#define BB     4
#define TT     2048

#define TBLK   16
#define EROWS  (TBLK + 2 * WSZ)   // 76
#define NTHR   1024

__device__ __forceinline__ float fast_tanh(float x) {
    float ax = fabsf(x);
    float t  = __expf(-2.0f * ax);
    float r  = (1.0f - t) * __builtin_amdgcn_rcpf(1.0f + t);
    return copysignf(r, x);
}

__device__ __forceinline__ float sigmoidf_(float x) {
    return __builtin_amdgcn_rcpf(1.0f + __expf(-x));
}

// ---------------- Pass 1: H = spec@W_h + b_attn ; E = spec@W_e ----------------
#define ROWS_HE 8
__global__ __launch_bounds__(256) void k_he(
        const float* __restrict__ spec,
        const float* __restrict__ W_h,
        const float* __restrict__ W_e,
        const float* __restrict__ b_attn,
        float* __restrict__ H,
        float* __restrict__ E) {
    const int tid = threadIdx.x;
    __shared__ float s[ROWS_HE * N_BINS];
    const float4* __restrict__ src4 =
        (const float4*)(spec + (size_t)blockIdx.x * (ROWS_HE * N_BINS));
    float4* s4 = (float4*)s;
#pragma unroll
    for (int i = 0; i < 2; ++i) {
        int idx = i * 256 + tid;
        if (idx < (ROWS_HE * N_BINS) / 4) s4[idx] = src4[idx];
    }
    __syncthreads();

    const int  m   = tid & 127;
    const bool isH = tid < 128;
    const float* __restrict__ Wp = (isH ? W_h : W_e) + m;
    const float bias = isH ? b_attn[m] : 0.0f;

    float acc[ROWS_HE];
#pragma unroll
    for (int r = 0; r < ROWS_HE; ++r) acc[r] = 0.0f;

#pragma unroll 4
    for (int f = 0; f < N_BINS; ++f) {
        float wv = Wp[f * MODEL];
#pragma unroll
        for (int r = 0; r < ROWS_HE; ++r)
            acc[r] = fmaf(s[r * N_BINS + f], wv, acc[r]);
    }

    float* __restrict__ dst =
        (isH ? H : E) + (size_t)blockIdx.x * ROWS_HE * MODEL + m;
#pragma unroll
    for (int r = 0; r < ROWS_HE; ++r) dst[r * MODEL] = acc[r] + bias;
}

// ---------------- Pass 2: halo-tiled scores/softmax/pooling/gemv ----------------
// One 1024-thread block = 16 waves = 16 consecutive t of one b.
// E halo (76 rows) staged in LDS with row-XOR swizzle; H tile + v_w staged
// with (q,g)-interleave so quad reads are broadcast.
__global__ __launch_bounds__(NTHR, 8) void k_attn(
        const float* __restrict__ spec,
        const float* __restrict__ H,
        const float* __restrict__ E,
        const float* __restrict__ v_w,
        const float* __restrict__ W1,
        const float* __restrict__ b1,
        float* __restrict__ pred,
        float* __restrict__ a_out) {
    const int tid  = threadIdx.x;
    const int wv   = tid >> 6;            // 0..15
    const int lane = tid & 63;
    const int blk  = blockIdx.x;          // 0..511
    const int b    = blk >> 7;            // 128 blocks per batch element
    const int t0   = (blk & 127) * TBLK;
    const int t    = t0 + wv;
    const int r    = b * TT + t;

    __shared__ float4 Es4[EROWS * 32];            // 38912 B (swizzled)
    __shared__ float4 Hs4[TBLK * 32];             //  8192 B (q,g-interleaved)
    __shared__ float4 vs4[32];                    //   512 B (q,g-interleaved)
    __shared__ float  scA[TBLK][WLEN];            //  3904 B
    __shared__ __hip_bfloat16 wsum[TBLK][232];    //  7424 B   (total 58944 B)

    // ---- stage E halo tile (zeros outside [0,TT)) ----
    const float4* __restrict__ Eb4 = (const float4*)E + (size_t)b * TT * 32;
    for (int i = tid; i < EROWS * 32; i += NTHR) {
        const int row = i >> 5, c4 = i & 31;
        const int s   = t0 + row - WSZ;
        float4 v = make_float4(0.f, 0.f, 0.f, 0.f);
        if (s >= 0 && s < TT) v = Eb4[(size_t)s * 32 + c4];
        Es4[(row << 5) + (c4 ^ (row & 7))] = v;
    }
    // ---- stage H tile and v_w, (q,g)-interleaved: chunk c4 -> (c4&7)*4 + (c4>>3) ----
    if (tid < TBLK * 32) {
        const int row = tid >> 5, c4 = tid & 31;
        const float4* __restrict__ Hb4 = (const float4*)H + (size_t)(b * TT + t0) * 32;
        Hs4[(row << 5) + ((c4 & 7) << 2) + (c4 >> 3)] = Hb4[(size_t)row * 32 + c4];
    } else if (tid < TBLK * 32 + 32) {
        const int c4 = tid - TBLK * 32;
        vs4[((c4 & 7) << 2) + (c4 >> 3)] = ((const float4*)v_w)[c4];
    }
    __syncthreads();

    // ---- scores: quad (g) owns m-chunk, w0 = lane>>2 windows, 4 its of 16 w ----
    const int g  = lane & 3;
    const int w0 = lane >> 2;
    int rbase[4];
#pragma unroll
    for (int it = 0; it < 4; ++it) {
        int row = wv + w0 + it * 16;
        if (row >= EROWS) row = 0;           // w>=61 lanes, masked later
        rbase[it] = row << 5;
    }
    float pp[4] = {0.f, 0.f, 0.f, 0.f};
#pragma unroll
    for (int q = 0; q < 8; ++q) {
        const float4 hq = Hs4[(wv << 5) + (q << 2) + g];
        const float4 vq = vs4[(q << 2) + g];
        const int    cq = (g << 3) + q;
#pragma unroll
        for (int it = 0; it < 4; ++it) {
            const int rb = rbase[it];
            const float4 ev = Es4[rb + (cq ^ ((rb >> 5) & 7))];
            pp[it] += fast_tanh(hq.x + ev.x) * vq.x
                    + fast_tanh(hq.y + ev.y) * vq.y
                    + fast_tanh(hq.z + ev.z) * vq.z
                    + fast_tanh(hq.w + ev.w) * vq.w;
        }
    }
#pragma unroll
    for (int it = 0; it < 4; ++it) {
        float p = pp[it];
        p += __shfl_xor(p, 1, 64);
        p += __shfl_xor(p, 2, 64);
        const int w = w0 + it * 16;
        if (g == 0 && w < WLEN) scA[wv][w] = p;
    }

    // ---- wave-local softmax over 61 scores ----
    float x = (lane < WLEN) ? scA[wv][lane] : -INFINITY;
    float mx = x;
#pragma unroll
    for (int d = 32; d >= 1; d >>= 1) mx = fmaxf(mx, __shfl_xor(mx, d, 64));
    float e = (lane < WLEN) ? __expf(x - mx) : 0.0f;
    float sm = e;
#pragma unroll
    for (int d = 32; d >= 1; d >>= 1) sm += __shfl_xor(sm, d, 64);
    const float a = e * __builtin_amdgcn_rcpf(sm);
    if (lane < WLEN) {
        a_out[(size_t)r * WLEN + lane] = a;
        const int sl = t + lane - WSZ;
        scA[wv][lane] = (sl >= 0 && sl < TT) ? a : 0.0f;   // aEff for pooling
    }

    // ---- pooling: lane owns 4 f-columns, spec from L2 ----
    const float* __restrict__ sb = spec + (size_t)b * TT * N_BINS;
    float a0 = 0.f, a1 = 0.f, a2 = 0.f, a3 = 0.f;
    const int f3 = (lane < 37) ? lane + 192 : 228;
#pragma unroll 4
    for (int w2 = 0; w2 < WLEN; ++w2) {
        const float av = scA[wv][w2];
        const int   s2 = min(max(t + w2 - WSZ, 0), TT - 1);
        const float* __restrict__ row = sb + (size_t)s2 * N_BINS;
        a0 = fmaf(av, row[lane      ], a0);
        a1 = fmaf(av, row[lane +  64], a1);
        a2 = fmaf(av, row[lane + 128], a2);
        a3 = fmaf(av, row[f3        ], a3);
    }
    wsum[wv][lane      ] = __float2bfloat16(a0);
    wsum[wv][lane +  64] = __float2bfloat16(a1);
    wsum[wv][lane + 128] = __float2bfloat16(a2);
    if (lane < 37) wsum[wv][lane + 192] = __float2bfloat16(a3);

    __syncthreads();

    // ---- gemv + sigmoid: 704 threads, each 2 rows; W1 loads shared block-wide ----
    if (tid < 8 * OUTD) {
        const int o  = tid % OUTD;
        const int rw = (tid / OUTD) * 2;
        float acc0 = b1[o], acc1 = acc0;
        const float* __restrict__ W1o = W1 + o;
#pragma unroll 4
        for (int f = 0; f < N_BINS; ++f) {
            const float w1v = W1o[f * OUTD];
            acc0 = fmaf(__bfloat162float(wsum[rw    ][f]), w1v, acc0);
            acc1 = fmaf(__bfloat162float(wsum[rw + 1][f]), w1v, acc1);
        }
        const size_t rr = (size_t)b * TT + t0 + rw;
        pred[rr * OUTD + o]       = sigmoidf_(acc0);
        pred[(rr + 1) * OUTD + o] = sigmoidf_(acc1);
    }
}

extern "C" void kernel_launch(void* const* d_in, const int* in_sizes, int n_in,
                              void* d_out, int out_size, void* d_ws, size_t ws_size,
                              hipStream_t stream) {
    const float* spec   = (const float*)d_in[0];
    const float* W_h    = (const float*)d_in[1];
    const float* W_e    = (const float*)d_in[2];
    const float* b_attn = (const float*)d_in[3];
    const float* v_w    = (const float*)d_in[4];
    const float* W1     = (const float*)d_in[5];
    const float* b1     = (const float*)d_in[6];

    const int n_rows = BB * TT;                    // 8192
    float* H = (float*)d_ws;                       // 4 MB
    float* E = H + (size_t)n_rows * MODEL;         // 4 MB

    float* pred  = (float*)d_out;                  // 8192*88
    float* a_out = pred + (size_t)n_rows * OUTD;   // 8192*61

    k_he  <<<n_rows / ROWS_HE, 256, 0, stream>>>(spec, W_h, W_e, b_attn, H, E);
    k_attn<<<n_rows / TBLK, NTHR, 0, stream>>>(spec, H, E, v_w, W1, b1, pred, a_out);
}

// Round 4
// 154.000 us; speedup vs baseline: 1.3725x; 1.3725x over previous
//
#include <hip/hip_runtime.h>
#include <hip/hip_bf16.h>
#include <math.h>

#define N_BINS 229
#define MODEL  128
#define OUTD   88
#define WSZ    30
#define WLEN   61
#define BB     4
#define TT     2048

#define TBLK   16
#define EROWS  (TBLK + 2 * WSZ)   // 76
#define NTHR   1024

__device__ __forceinline__ float fast_tanh(float x) {
    float ax = fabsf(x);
    float t  = __expf(-2.0f * ax);
    float r  = (1.0f - t) * __builtin_amdgcn_rcpf(1.0f + t);
    return copysignf(r, x);
}

__device__ __forceinline__ float sigmoidf_(float x) {
    return __builtin_amdgcn_rcpf(1.0f + __expf(-x));
}

// ---------------- Pass 1: H = spec@W_h + b_attn ; E = spec@W_e ----------------
#define ROWS_HE 8
__global__ __launch_bounds__(256) void k_he(
        const float* __restrict__ spec,
        const float* __restrict__ W_h,
        const float* __restrict__ W_e,
        const float* __restrict__ b_attn,
        float* __restrict__ H,
        float* __restrict__ E) {
    const int tid = threadIdx.x;
    __shared__ float s[ROWS_HE * N_BINS];
    const float4* __restrict__ src4 =
        (const float4*)(spec + (size_t)blockIdx.x * (ROWS_HE * N_BINS));
    float4* s4 = (float4*)s;
#pragma unroll
    for (int i = 0; i < 2; ++i) {
        int idx = i * 256 + tid;
        if (idx < (ROWS_HE * N_BINS) / 4) s4[idx] = src4[idx];
    }
    __syncthreads();

    const int  m   = tid & 127;
    const bool isH = tid < 128;
    const float* __restrict__ Wp = (isH ? W_h : W_e) + m;
    const float bias = isH ? b_attn[m] : 0.0f;

    float acc[ROWS_HE];
#pragma unroll
    for (int r = 0; r < ROWS_HE; ++r) acc[r] = 0.0f;

#pragma unroll 4
    for (int f = 0; f < N_BINS; ++f) {
        float wv = Wp[f * MODEL];
#pragma unroll
        for (int r = 0; r < ROWS_HE; ++r)
            acc[r] = fmaf(s[r * N_BINS + f], wv, acc[r]);
    }

    float* __restrict__ dst =
        (isH ? H : E) + (size_t)blockIdx.x * ROWS_HE * MODEL + m;
#pragma unroll
    for (int r = 0; r < ROWS_HE; ++r) dst[r * MODEL] = acc[r] + bias;
}

// ---------------- Pass 2: halo-tiled scores/softmax/pooling/gemv ----------------
// One 1024-thread block = 16 waves = 16 consecutive t of one b.
// E halo (76 rows) staged once in LDS with row-XOR swizzle; quad lane g owns
// m-chunks cq = 4q+g so the 4 quad lanes hit 4 distinct LDS bank groups.
// launch_bounds(1024,4): VGPR cap 128 -> no scratch spills (round-3 lesson).
__global__ __launch_bounds__(NTHR, 4) void k_attn(
        const float* __restrict__ spec,
        const float* __restrict__ H,
        const float* __restrict__ E,
        const float* __restrict__ v_w,
        const float* __restrict__ W1,
        const float* __restrict__ b1,
        float* __restrict__ pred,
        float* __restrict__ a_out) {
    const int tid  = threadIdx.x;
    const int wv   = tid >> 6;            // 0..15
    const int lane = tid & 63;
    const int blk  = blockIdx.x;          // 0..511
    const int b    = blk >> 7;            // 128 blocks per batch element
    const int t0   = (blk & 127) * TBLK;
    const int t    = t0 + wv;
    const int r    = b * TT + t;

    __shared__ float4 Es4[EROWS * 32];            // 38912 B (row-XOR swizzled)
    __shared__ float4 Hs4[TBLK * 32];             //  8192 B (linear)
    __shared__ float4 vs4[32];                    //   512 B (linear)
    __shared__ float  scA[TBLK][WLEN];            //  3904 B
    __shared__ __hip_bfloat16 wsum[TBLK][232];    //  7424 B   (total 58944 B)

    // ---- stage E halo tile (zeros outside [0,TT)) ----
    const float4* __restrict__ Eb4 = (const float4*)E + (size_t)b * TT * 32;
    for (int i = tid; i < EROWS * 32; i += NTHR) {
        const int row = i >> 5, c4 = i & 31;
        const int s   = t0 + row - WSZ;
        float4 v = make_float4(0.f, 0.f, 0.f, 0.f);
        if (s >= 0 && s < TT) v = Eb4[(size_t)s * 32 + c4];
        Es4[(row << 5) + (c4 ^ (row & 7))] = v;
    }
    // ---- stage H tile and v_w (linear; reads are wave-broadcast) ----
    if (tid < TBLK * 32) {
        const float4* __restrict__ Hb4 = (const float4*)H + (size_t)(b * TT + t0) * 32;
        Hs4[tid] = Hb4[tid];
    } else if (tid < TBLK * 32 + 32) {
        vs4[tid - TBLK * 32] = ((const float4*)v_w)[tid - TBLK * 32];
    }
    __syncthreads();

    // ---- scores: quad lane g owns chunks cq=4q+g; w0 = lane>>2; 4 its x 16 w ----
    const int g  = lane & 3;
    const int w0 = lane >> 2;
    int rowv[4];
#pragma unroll
    for (int it = 0; it < 4; ++it) {
        int row = wv + w0 + it * 16;
        if (row >= EROWS) row = 0;           // w>=61 lanes, masked at write
        rowv[it] = row;
    }
    float pp[4] = {0.f, 0.f, 0.f, 0.f};
#pragma unroll
    for (int q = 0; q < 8; ++q) {
        const int    cq = (q << 2) + g;      // 4 quad lanes -> 4 distinct bank groups
        const float4 hq = Hs4[(wv << 5) + cq];
        const float4 vq = vs4[cq];
#pragma unroll
        for (int it = 0; it < 4; ++it) {
            const int row = rowv[it];
            const float4 ev = Es4[(row << 5) + (cq ^ (row & 7))];
            pp[it] += fast_tanh(hq.x + ev.x) * vq.x
                    + fast_tanh(hq.y + ev.y) * vq.y
                    + fast_tanh(hq.z + ev.z) * vq.z
                    + fast_tanh(hq.w + ev.w) * vq.w;
        }
    }
#pragma unroll
    for (int it = 0; it < 4; ++it) {
        float p = pp[it];
        p += __shfl_xor(p, 1, 64);
        p += __shfl_xor(p, 2, 64);
        const int w = w0 + it * 16;
        if (g == 0 && w < WLEN) scA[wv][w] = p;
    }

    // ---- wave-local softmax over 61 scores ----
    float x = (lane < WLEN) ? scA[wv][lane] : -INFINITY;
    float mx = x;
#pragma unroll
    for (int d = 32; d >= 1; d >>= 1) mx = fmaxf(mx, __shfl_xor(mx, d, 64));
    float e = (lane < WLEN) ? __expf(x - mx) : 0.0f;
    float sm = e;
#pragma unroll
    for (int d = 32; d >= 1; d >>= 1) sm += __shfl_xor(sm, d, 64);
    const float a = e * __builtin_amdgcn_rcpf(sm);
    if (lane < WLEN) {
        a_out[(size_t)r * WLEN + lane] = a;
        const int sl = t + lane - WSZ;
        scA[wv][lane] = (sl >= 0 && sl < TT) ? a : 0.0f;   // aEff for pooling
    }

    // ---- pooling: lane owns 4 f-columns, spec from L2 ----
    const float* __restrict__ sb = spec + (size_t)b * TT * N_BINS;
    float a0 = 0.f, a1 = 0.f, a2 = 0.f, a3 = 0.f;
    const int f3 = (lane < 37) ? lane + 192 : 228;
#pragma unroll 4
    for (int w2 = 0; w2 < WLEN; ++w2) {
        const float av = scA[wv][w2];
        const int   s2 = min(max(t + w2 - WSZ, 0), TT - 1);
        const float* __restrict__ row = sb + (size_t)s2 * N_BINS;
        a0 = fmaf(av, row[lane      ], a0);
        a1 = fmaf(av, row[lane +  64], a1);
        a2 = fmaf(av, row[lane + 128], a2);
        a3 = fmaf(av, row[f3        ], a3);
    }
    wsum[wv][lane      ] = __float2bfloat16(a0);
    wsum[wv][lane +  64] = __float2bfloat16(a1);
    wsum[wv][lane + 128] = __float2bfloat16(a2);
    if (lane < 37) wsum[wv][lane + 192] = __float2bfloat16(a3);

    __syncthreads();

    // ---- gemv + sigmoid: 704 threads, each 2 rows; W1 loads shared block-wide ----
    if (tid < 8 * OUTD) {
        const int o  = tid % OUTD;
        const int rw = (tid / OUTD) * 2;
        float acc0 = b1[o], acc1 = acc0;
        const float* __restrict__ W1o = W1 + o;
#pragma unroll 4
        for (int f = 0; f < N_BINS; ++f) {
            const float w1v = W1o[f * OUTD];
            acc0 = fmaf(__bfloat162float(wsum[rw    ][f]), w1v, acc0);
            acc1 = fmaf(__bfloat162float(wsum[rw + 1][f]), w1v, acc1);
        }
        const size_t rr = (size_t)b * TT + t0 + rw;
        pred[rr * OUTD + o]       = sigmoidf_(acc0);
        pred[(rr + 1) * OUTD + o] = sigmoidf_(acc1);
    }
}

extern "C" void kernel_launch(void* const* d_in, const int* in_sizes, int n_in,
                              void* d_out, int out_size, void* d_ws, size_t ws_size,
                              hipStream_t stream) {
    const float* spec   = (const float*)d_in[0];
    const float* W_h    = (const float*)d_in[1];
    const float* W_e    = (const float*)d_in[2];
    const float* b_attn = (const float*)d_in[3];
    const float* v_w    = (const float*)d_in[4];
    const float* W1     = (const float*)d_in[5];
    const float* b1     = (const float*)d_in[6];

    const int n_rows = BB * TT;                    // 8192
    float* H = (float*)d_ws;                       // 4 MB
    float* E = H + (size_t)n_rows * MODEL;         // 4 MB

    float* pred  = (float*)d_out;                  // 8192*88
    float* a_out = pred + (size_t)n_rows * OUTD;   // 8192*61

    k_he  <<<n_rows / ROWS_HE, 256, 0, stream>>>(spec, W_h, W_e, b_attn, H, E);
    k_attn<<<n_rows / TBLK, NTHR, 0, stream>>>(spec, H, E, v_w, W1, b1, pred, a_out);
}

// Round 5
// 136.931 us; speedup vs baseline: 1.5435x; 1.1247x over previous
//
#include <hip/hip_runtime.h>
#include <math.h>

#define N_BINS 229
#define MODEL  128
#define OUTD   88
#define WSZ    30
#define WLEN   61
#define BB     4
#define TT     2048
#define CTANH  2.8853900817779268f   // 2*log2(e)

__device__ __forceinline__ float sigmoidf_(float x) {
    return __builtin_amdgcn_rcpf(1.0f + __expf(-x));
}

// ---------------- Pass 1: H = spec@W_h + b_attn ; E = spec@W_e ----------------
// 8 rows/block staged in LDS; thread = output column; f unrolled x8 so 8 W loads
// are in flight per 64 FMAs.
#define ROWS_HE 8
__global__ __launch_bounds__(256) void k_he(
        const float* __restrict__ spec,
        const float* __restrict__ W_h,
        const float* __restrict__ W_e,
        const float* __restrict__ b_attn,
        float* __restrict__ H,
        float* __restrict__ E) {
    const int tid = threadIdx.x;
    __shared__ float s[ROWS_HE * N_BINS];
    const float4* __restrict__ src4 =
        (const float4*)(spec + (size_t)blockIdx.x * (ROWS_HE * N_BINS));
    float4* s4 = (float4*)s;
#pragma unroll
    for (int i = 0; i < 2; ++i) {
        int idx = i * 256 + tid;
        if (idx < (ROWS_HE * N_BINS) / 4) s4[idx] = src4[idx];
    }
    __syncthreads();

    const int  m   = tid & 127;
    const bool isH = tid < 128;
    const float* __restrict__ Wp = (isH ? W_h : W_e) + m;
    const float bias = isH ? b_attn[m] : 0.0f;

    float acc[ROWS_HE];
#pragma unroll
    for (int r = 0; r < ROWS_HE; ++r) acc[r] = 0.0f;

    int f0 = 0;
    for (; f0 + 8 <= N_BINS; f0 += 8) {          // 28 iterations
        float wr[8];
#pragma unroll
        for (int j = 0; j < 8; ++j) wr[j] = Wp[(f0 + j) * MODEL];
#pragma unroll
        for (int j = 0; j < 8; ++j)
#pragma unroll
            for (int r = 0; r < ROWS_HE; ++r)
                acc[r] = fmaf(s[r * N_BINS + f0 + j], wr[j], acc[r]);
    }
    for (; f0 < N_BINS; ++f0) {                  // 5-wide tail
        const float wv = Wp[f0 * MODEL];
#pragma unroll
        for (int r = 0; r < ROWS_HE; ++r)
            acc[r] = fmaf(s[r * N_BINS + f0], wv, acc[r]);
    }

    float* __restrict__ dst =
        (isH ? H : E) + (size_t)blockIdx.x * ROWS_HE * MODEL + m;
#pragma unroll
    for (int r = 0; r < ROWS_HE; ++r) dst[r * MODEL] = acc[r] + bias;
}

// ---------------- Pass 2 score phase (templated boundary handling) ----------------
// Per wave = one row t. Quad lane g owns m-chunks cq=4q+g; w0=lane>>2 covers
// windows w0+16*it. tanh(y)*v = v - 2v*rcp(exp2(C*y)+1); Sum(v) hoisted out.
template <bool SAFE>
__device__ __forceinline__ void score_phase(
        const float4* __restrict__ Eb4,     // batch base, rows of 32 float4
        const float4* __restrict__ Hs4w,    // this wave's H row (32 float4)
        const float4* __restrict__ Vs4,     // v_w (32 float4)
        int t, int g, int w0, float* __restrict__ scrow) {
    const float4* er[4];
    bool ok[4];
#pragma unroll
    for (int it = 0; it < 4; ++it) {
        const int w = w0 + it * 16;
        const int s = t + w - WSZ;
        if (SAFE) {
            ok[it] = (s >= 0) && (s < TT);
            const int sCl = min(max(s, 0), TT - 1);
            er[it] = Eb4 + (size_t)sCl * 32 + g;
        } else {
            // t in [30, 2014]: s in [0,2047] even for the junk lanes w=61..63
            er[it] = Eb4 + (size_t)s * 32 + g;
        }
    }

    float pp[4] = {0.f, 0.f, 0.f, 0.f};
    float vs = 0.f;
#pragma unroll
    for (int q = 0; q < 8; ++q) {
        const int    cq = (q << 2) + g;
        const float4 hq = Hs4w[cq];          // broadcast within 16-lane groups
        const float4 vq = Vs4[cq];
        vs += (vq.x + vq.y) + (vq.z + vq.w);
        const float hcx = hq.x * CTANH, hcy = hq.y * CTANH,
                    hcz = hq.z * CTANH, hcw = hq.w * CTANH;
        const float nvx = -2.f * vq.x, nvy = -2.f * vq.y,
                    nvz = -2.f * vq.z, nvw = -2.f * vq.w;
#pragma unroll
        for (int it = 0; it < 4; ++it) {
            float4 ev = er[it][q << 2];      // 64B coalesced per quad
            if (SAFE && !ok[it]) ev = make_float4(0.f, 0.f, 0.f, 0.f);
            float u;
            u = __builtin_amdgcn_rcpf(
                    __builtin_amdgcn_exp2f(fminf(fmaf(ev.x, CTANH, hcx), 126.f)) + 1.f);
            pp[it] = fmaf(nvx, u, pp[it]);
            u = __builtin_amdgcn_rcpf(
                    __builtin_amdgcn_exp2f(fminf(fmaf(ev.y, CTANH, hcy), 126.f)) + 1.f);
            pp[it] = fmaf(nvy, u, pp[it]);
            u = __builtin_amdgcn_rcpf(
                    __builtin_amdgcn_exp2f(fminf(fmaf(ev.z, CTANH, hcz), 126.f)) + 1.f);
            pp[it] = fmaf(nvz, u, pp[it]);
            u = __builtin_amdgcn_rcpf(
                    __builtin_amdgcn_exp2f(fminf(fmaf(ev.w, CTANH, hcw), 126.f)) + 1.f);
            pp[it] = fmaf(nvw, u, pp[it]);
        }
    }

    vs += __shfl_xor(vs, 1, 64);
    vs += __shfl_xor(vs, 2, 64);
#pragma unroll
    for (int it = 0; it < 4; ++it) {
        float p = pp[it];
        p += __shfl_xor(p, 1, 64);
        p += __shfl_xor(p, 2, 64);
        const int w = w0 + it * 16;
        if (g == 0 && w < WLEN) scrow[w] = p + vs;
    }
}

// ---------------- Pass 2: scores -> softmax -> pooling -> gemv ----------------
__global__ __launch_bounds__(256) void k_attn(
        const float* __restrict__ spec,
        const float* __restrict__ H,
        const float* __restrict__ E,
        const float* __restrict__ v_w,
        const float* __restrict__ W1,
        const float* __restrict__ b1,
        float* __restrict__ pred,
        float* __restrict__ a_out) {
    const int tid  = threadIdx.x;
    const int wv   = tid >> 6;
    const int lane = tid & 63;
    const int r0   = blockIdx.x * 4;
    const int r    = r0 + wv;
    const int b    = r >> 11;               // T = 2048
    const int t    = r & (TT - 1);

    __shared__ float4 Hs4[4 * 32];          // 2 KB
    __shared__ float4 Vs4[32];              // 512 B
    __shared__ float  scA[4][64];           // 1 KB
    __shared__ float  wsum[4][232];         // 3.7 KB

    if (tid < 128)       Hs4[tid]       = ((const float4*)H)[(size_t)r0 * 32 + tid];
    else if (tid < 160)  Vs4[tid - 128] = ((const float4*)v_w)[tid - 128];
    __syncthreads();

    const int g  = lane & 3;
    const int w0 = lane >> 2;
    const float4* __restrict__ Eb4 = (const float4*)E + (size_t)b * TT * 32;

    if (t >= WSZ && t <= TT - 1 - 33)       // fast interior path, wave-uniform
        score_phase<false>(Eb4, &Hs4[wv * 32], Vs4, t, g, w0, scA[wv]);
    else
        score_phase<true >(Eb4, &Hs4[wv * 32], Vs4, t, g, w0, scA[wv]);

    // ---- wave-local softmax over 61 scores ----
    float x = (lane < WLEN) ? scA[wv][lane] : -INFINITY;
    float mx = x;
#pragma unroll
    for (int d = 32; d >= 1; d >>= 1) mx = fmaxf(mx, __shfl_xor(mx, d, 64));
    float e = (lane < WLEN) ? __expf(x - mx) : 0.0f;
    float sm = e;
#pragma unroll
    for (int d = 32; d >= 1; d >>= 1) sm += __shfl_xor(sm, d, 64);
    const float a = e * __builtin_amdgcn_rcpf(sm);
    if (lane < WLEN) a_out[(size_t)r * WLEN + lane] = a;
    const int sl = t + lane - WSZ;
    scA[wv][lane] = (lane < WLEN && sl >= 0 && sl < TT) ? a : 0.0f;

    // ---- pooling: lane owns 4 f-columns; 4 independent loads / iter ----
    const float* __restrict__ sb = spec + (size_t)b * TT * N_BINS;
    float a0 = 0.f, a1 = 0.f, a2 = 0.f, a3 = 0.f;
    const int f3 = (lane < 37) ? lane + 192 : 228;
#pragma unroll 8
    for (int w2 = 0; w2 < WLEN; ++w2) {
        const float av = scA[wv][w2];                  // LDS broadcast
        const int   s2 = min(max(t + w2 - WSZ, 0), TT - 1);
        const float* __restrict__ row = sb + (size_t)s2 * N_BINS;
        a0 = fmaf(av, row[lane      ], a0);
        a1 = fmaf(av, row[lane +  64], a1);
        a2 = fmaf(av, row[lane + 128], a2);
        a3 = fmaf(av, row[f3        ], a3);
    }
    wsum[wv][lane      ] = a0;
    wsum[wv][lane +  64] = a1;
    wsum[wv][lane + 128] = a2;
    if (lane < 37) wsum[wv][lane + 192] = a3;

    __syncthreads();

    // ---- gemv + sigmoid: 176 threads, 2 rows each; W1 loads coalesced ----
    if (tid < 176) {
        const int o  = (tid >= 88) ? tid - 88 : tid;
        const int rw = (tid >= 88) ? 2 : 0;
        float acc0 = b1[o], acc1 = acc0;
        const float* __restrict__ W1o = W1 + o;
#pragma unroll 4
        for (int f = 0; f < N_BINS; ++f) {
            const float w1v = W1o[f * OUTD];
            acc0 = fmaf(wsum[rw    ][f], w1v, acc0);
            acc1 = fmaf(wsum[rw + 1][f], w1v, acc1);
        }
        const size_t rr = (size_t)r0 + rw;
        pred[rr * OUTD + o]       = sigmoidf_(acc0);
        pred[(rr + 1) * OUTD + o] = sigmoidf_(acc1);
    }
}

extern "C" void kernel_launch(void* const* d_in, const int* in_sizes, int n_in,
                              void* d_out, int out_size, void* d_ws, size_t ws_size,
                              hipStream_t stream) {
    const float* spec   = (const float*)d_in[0];
    const float* W_h    = (const float*)d_in[1];
    const float* W_e    = (const float*)d_in[2];
    const float* b_attn = (const float*)d_in[3];
    const float* v_w    = (const float*)d_in[4];
    const float* W1     = (const float*)d_in[5];
    const float* b1     = (const float*)d_in[6];

    const int n_rows = BB * TT;                    // 8192
    float* H = (float*)d_ws;                       // 4 MB
    float* E = H + (size_t)n_rows * MODEL;         // 4 MB

    float* pred  = (float*)d_out;                  // 8192*88
    float* a_out = pred + (size_t)n_rows * OUTD;   // 8192*61

    k_he  <<<n_rows / ROWS_HE, 256, 0, stream>>>(spec, W_h, W_e, b_attn, H, E);
    k_attn<<<n_rows / 4,       256, 0, stream>>>(spec, H, E, v_w, W1, b1, pred, a_out);
}

// Round 6
// 131.361 us; speedup vs baseline: 1.6090x; 1.0424x over previous
//
#include <hip/hip_runtime.h>
#include <math.h>

#define N_BINS 229
#define MODEL  128
#define OUTD   88
#define WSZ    30
#define WLEN   61
#define BB     4
#define TT     2048
#define CTANH  2.8853900817779268f   // 2*log2(e)

__device__ __forceinline__ float sigmoidf_(float x) {
    return __builtin_amdgcn_rcpf(1.0f + __expf(-x));
}

// ---------------- Pass 1: H = spec@W_h + b_attn ; E = spec@W_e ----------------
// 16 rows/block staged in LDS; thread = output column; f unrolled x8.
#define ROWS_HE 16
__global__ __launch_bounds__(256) void k_he(
        const float* __restrict__ spec,
        const float* __restrict__ W_h,
        const float* __restrict__ W_e,
        const float* __restrict__ b_attn,
        float* __restrict__ H,
        float* __restrict__ E) {
    const int tid = threadIdx.x;
    __shared__ float s[ROWS_HE * N_BINS];              // 14656 B
    const float4* __restrict__ src4 =
        (const float4*)(spec + (size_t)blockIdx.x * (ROWS_HE * N_BINS));
    float4* s4 = (float4*)s;
#pragma unroll
    for (int i = 0; i < 4; ++i) {                      // 916 float4 / 256 thr
        int idx = i * 256 + tid;
        if (idx < (ROWS_HE * N_BINS) / 4) s4[idx] = src4[idx];
    }
    __syncthreads();

    const int  m   = tid & 127;
    const bool isH = tid < 128;
    const float* __restrict__ Wp = (isH ? W_h : W_e) + m;
    const float bias = isH ? b_attn[m] : 0.0f;

    float acc[ROWS_HE];
#pragma unroll
    for (int r = 0; r < ROWS_HE; ++r) acc[r] = 0.0f;

    int f0 = 0;
    for (; f0 + 8 <= N_BINS; f0 += 8) {
        float wr[8];
#pragma unroll
        for (int j = 0; j < 8; ++j) wr[j] = Wp[(f0 + j) * MODEL];
#pragma unroll
        for (int j = 0; j < 8; ++j)
#pragma unroll
            for (int r = 0; r < ROWS_HE; ++r)
                acc[r] = fmaf(s[r * N_BINS + f0 + j], wr[j], acc[r]);
    }
    for (; f0 < N_BINS; ++f0) {
        const float wv = Wp[f0 * MODEL];
#pragma unroll
        for (int r = 0; r < ROWS_HE; ++r)
            acc[r] = fmaf(s[r * N_BINS + f0], wv, acc[r]);
    }

    float* __restrict__ dst =
        (isH ? H : E) + (size_t)blockIdx.x * ROWS_HE * MODEL + m;
#pragma unroll
    for (int r = 0; r < ROWS_HE; ++r) dst[r * MODEL] = acc[r] + bias;
}

// ---------------- Pass 2 score phase for a ROW PAIR (t, t+1) ----------------
// Each loaded E float4 at s = t+w-30 (w = w0+16*it, w in 0..63) serves
// row t (window w) and row t+1 (window w-1). tanh via exp2: tanh(y)*v =
// v - 2v*rcp(exp2(C*y)+1), Sum(v) hoisted.
template <bool SAFE>
__device__ __forceinline__ void score_pair(
        const float4* __restrict__ Eb4,     // batch base (rows of 32 float4)
        const float4* __restrict__ HsT,     // H row t   (32 float4, LDS)
        const float4* __restrict__ HsU,     // H row t+1 (32 float4, LDS)
        const float4* __restrict__ Vs4,     // v_w (32 float4, LDS)
        int t, int g, int w0,
        float* __restrict__ scT, float* __restrict__ scU) {
    const float4* er[4];
    bool ok[4];
#pragma unroll
    for (int it = 0; it < 4; ++it) {
        const int w = w0 + it * 16;
        const int s = t + w - WSZ;
        if (SAFE) {
            ok[it] = (s >= 0) && (s < TT);
            er[it] = Eb4 + (size_t)min(max(s, 0), TT - 1) * 32 + g;
        } else {
            er[it] = Eb4 + (size_t)s * 32 + g;   // t in [30,2014]: s in [0,2047]
        }
    }

    float ppT[4] = {0.f, 0.f, 0.f, 0.f};
    float ppU[4] = {0.f, 0.f, 0.f, 0.f};
    float vs = 0.f;
#pragma unroll
    for (int q = 0; q < 8; ++q) {
        const int    cq = (q << 2) + g;          // 4 distinct bank groups/quad
        const float4 hT = HsT[cq];
        const float4 hU = HsU[cq];
        const float4 vq = Vs4[cq];
        vs += (vq.x + vq.y) + (vq.z + vq.w);
        const float nx = -2.f * vq.x, ny = -2.f * vq.y,
                    nz = -2.f * vq.z, nw = -2.f * vq.w;
        const float aTx = hT.x * CTANH, aTy = hT.y * CTANH,
                    aTz = hT.z * CTANH, aTw = hT.w * CTANH;
        const float aUx = hU.x * CTANH, aUy = hU.y * CTANH,
                    aUz = hU.z * CTANH, aUw = hU.w * CTANH;
#pragma unroll
        for (int it = 0; it < 4; ++it) {
            float4 ev = er[it][q << 2];
            if (SAFE && !ok[it]) ev = make_float4(0.f, 0.f, 0.f, 0.f);
            const float ex = ev.x * CTANH, ey = ev.y * CTANH,
                        ez = ev.z * CTANH, ew = ev.w * CTANH;
            float u;
            u = __builtin_amdgcn_rcpf(__builtin_amdgcn_exp2f(fminf(ex + aTx, 126.f)) + 1.f);
            ppT[it] = fmaf(nx, u, ppT[it]);
            u = __builtin_amdgcn_rcpf(__builtin_amdgcn_exp2f(fminf(ex + aUx, 126.f)) + 1.f);
            ppU[it] = fmaf(nx, u, ppU[it]);
            u = __builtin_amdgcn_rcpf(__builtin_amdgcn_exp2f(fminf(ey + aTy, 126.f)) + 1.f);
            ppT[it] = fmaf(ny, u, ppT[it]);
            u = __builtin_amdgcn_rcpf(__builtin_amdgcn_exp2f(fminf(ey + aUy, 126.f)) + 1.f);
            ppU[it] = fmaf(ny, u, ppU[it]);
            u = __builtin_amdgcn_rcpf(__builtin_amdgcn_exp2f(fminf(ez + aTz, 126.f)) + 1.f);
            ppT[it] = fmaf(nz, u, ppT[it]);
            u = __builtin_amdgcn_rcpf(__builtin_amdgcn_exp2f(fminf(ez + aUz, 126.f)) + 1.f);
            ppU[it] = fmaf(nz, u, ppU[it]);
            u = __builtin_amdgcn_rcpf(__builtin_amdgcn_exp2f(fminf(ew + aTw, 126.f)) + 1.f);
            ppT[it] = fmaf(nw, u, ppT[it]);
            u = __builtin_amdgcn_rcpf(__builtin_amdgcn_exp2f(fminf(ew + aUw, 126.f)) + 1.f);
            ppU[it] = fmaf(nw, u, ppU[it]);
        }
    }

    vs += __shfl_xor(vs, 1, 64);
    vs += __shfl_xor(vs, 2, 64);
#pragma unroll
    for (int it = 0; it < 4; ++it) {
        float pT = ppT[it];
        pT += __shfl_xor(pT, 1, 64);
        pT += __shfl_xor(pT, 2, 64);
        float pU = ppU[it];
        pU += __shfl_xor(pU, 1, 64);
        pU += __shfl_xor(pU, 2, 64);
        const int w = w0 + it * 16;
        if (g == 0) {
            if (w < WLEN)            scT[w]     = pT + vs;
            if (w >= 1 && w <= WLEN) scU[w - 1] = pU + vs;
        }
    }
}

// ---------------- Pass 2: wave = row pair; block = 8 rows ----------------
__global__ __launch_bounds__(256) void k_attn(
        const float* __restrict__ spec,
        const float* __restrict__ H,
        const float* __restrict__ E,
        const float* __restrict__ v_w,
        const float* __restrict__ W1,
        const float* __restrict__ b1,
        float* __restrict__ pred,
        float* __restrict__ a_out) {
    const int tid  = threadIdx.x;
    const int wv   = tid >> 6;
    const int lane = tid & 63;
    const int r0   = blockIdx.x * 8;
    const int rT   = r0 + wv * 2;
    const int b    = rT >> 11;              // T = 2048
    const int t    = rT & (TT - 1);

    __shared__ float4 Hs4[8 * 32];          // 4 KB
    __shared__ float4 Vs4[32];              // 512 B
    __shared__ float  scA[4][2][64];        // 2 KB
    __shared__ float  wsum[4][2][232];      // 7.4 KB

    Hs4[tid] = ((const float4*)H)[(size_t)r0 * 32 + tid];   // exactly 256
    if (tid < 32) Vs4[tid] = ((const float4*)v_w)[tid];
    __syncthreads();

    const int g  = lane & 3;
    const int w0 = lane >> 2;
    const float4* __restrict__ Eb4 = (const float4*)E + (size_t)b * TT * 32;

    if (t >= WSZ && t <= TT - 1 - 33)       // wave-uniform interior fast path
        score_pair<false>(Eb4, &Hs4[(wv * 2) * 32], &Hs4[(wv * 2 + 1) * 32],
                          Vs4, t, g, w0, scA[wv][0], scA[wv][1]);
    else
        score_pair<true >(Eb4, &Hs4[(wv * 2) * 32], &Hs4[(wv * 2 + 1) * 32],
                          Vs4, t, g, w0, scA[wv][0], scA[wv][1]);

    // ---- softmax, both rows; store aEff (row u shifted by +1 for sharing) ----
#pragma unroll
    for (int rr = 0; rr < 2; ++rr) {
        float x = (lane < WLEN) ? scA[wv][rr][lane] : -INFINITY;
        float mx = x;
#pragma unroll
        for (int d = 32; d >= 1; d >>= 1) mx = fmaxf(mx, __shfl_xor(mx, d, 64));
        float e = (lane < WLEN) ? __expf(x - mx) : 0.0f;
        float sm = e;
#pragma unroll
        for (int d = 32; d >= 1; d >>= 1) sm += __shfl_xor(sm, d, 64);
        const float a = e * __builtin_amdgcn_rcpf(sm);
        if (lane < WLEN) a_out[(size_t)(rT + rr) * WLEN + lane] = a;
        const int   sl   = (t + rr) + lane - WSZ;
        const float aval = (lane < WLEN && sl >= 0 && sl < TT) ? a : 0.0f;
        if (rr == 0) {
            scA[wv][0][lane] = aval;                 // slots 61..63 = 0
        } else {
            scA[wv][1][lane] = 0.0f;                 // zero all 64 slots
            if (lane < WLEN) scA[wv][1][lane + 1] = aval;   // shift: aU[w]=a_u[w-1]
        }
    }

    // ---- pooling: 62 shared row-loads serve both rows (8 FMAs per load) ----
    const float* __restrict__ sb = spec + (size_t)b * TT * N_BINS;
    float t0a = 0.f, t1a = 0.f, t2a = 0.f, t3a = 0.f;
    float u0a = 0.f, u1a = 0.f, u2a = 0.f, u3a = 0.f;
    const int f3 = (lane < 37) ? lane + 192 : 228;
#pragma unroll 4
    for (int w2 = 0; w2 < 62; ++w2) {
        const float at = scA[wv][0][w2];             // LDS broadcast
        const float au = scA[wv][1][w2];
        const int   s2 = min(max(t + w2 - WSZ, 0), TT - 1);
        const float* __restrict__ row = sb + (size_t)s2 * N_BINS;
        const float c0 = row[lane      ];
        const float c1 = row[lane +  64];
        const float c2 = row[lane + 128];
        const float c3 = row[f3        ];
        t0a = fmaf(at, c0, t0a);  u0a = fmaf(au, c0, u0a);
        t1a = fmaf(at, c1, t1a);  u1a = fmaf(au, c1, u1a);
        t2a = fmaf(at, c2, t2a);  u2a = fmaf(au, c2, u2a);
        t3a = fmaf(at, c3, t3a);  u3a = fmaf(au, c3, u3a);
    }
    wsum[wv][0][lane      ] = t0a;   wsum[wv][1][lane      ] = u0a;
    wsum[wv][0][lane +  64] = t1a;   wsum[wv][1][lane +  64] = u1a;
    wsum[wv][0][lane + 128] = t2a;   wsum[wv][1][lane + 128] = u2a;
    if (lane < 37) { wsum[wv][0][lane + 192] = t3a; wsum[wv][1][lane + 192] = u3a; }

    __syncthreads();

    // ---- gemv + sigmoid: 176 threads, 4 rows each; W1 loads broadcast ----
    if (tid < 176) {
        const int h = (tid >= 88) ? 1 : 0;
        const int o = tid - h * 88;
        const float* __restrict__ ws = &wsum[0][0][0] + h * 4 * 232;
        float acc0 = b1[o], acc1 = acc0, acc2 = acc0, acc3 = acc0;
        const float* __restrict__ W1o = W1 + o;
#pragma unroll 4
        for (int f = 0; f < N_BINS; ++f) {
            const float w1v = W1o[f * OUTD];
            acc0 = fmaf(ws[f      ], w1v, acc0);
            acc1 = fmaf(ws[f + 232], w1v, acc1);
            acc2 = fmaf(ws[f + 464], w1v, acc2);
            acc3 = fmaf(ws[f + 696], w1v, acc3);
        }
        const size_t rb = (size_t)r0 + h * 4;
        pred[(rb + 0) * OUTD + o] = sigmoidf_(acc0);
        pred[(rb + 1) * OUTD + o] = sigmoidf_(acc1);
        pred[(rb + 2) * OUTD + o] = sigmoidf_(acc2);
        pred[(rb + 3) * OUTD + o] = sigmoidf_(acc3);
    }
}

extern "C" void kernel_launch(void* const* d_in, const int* in_sizes, int n_in,
                              void* d_out, int out_size, void* d_ws, size_t ws_size,
                              hipStream_t stream) {
    const float* spec   = (const float*)d_in[0];
    const float* W_h    = (const float*)d_in[1];
    const float* W_e    = (const float*)d_in[2];
    const float* b_attn = (const float*)d_in[3];
    const float* v_w    = (const float*)d_in[4];
    const float* W1     = (const float*)d_in[5];
    const float* b1     = (const float*)d_in[6];

    const int n_rows = BB * TT;                    // 8192
    float* H = (float*)d_ws;                       // 4 MB
    float* E = H + (size_t)n_rows * MODEL;         // 4 MB

    float* pred  = (float*)d_out;                  // 8192*88
    float* a_out = pred + (size_t)n_rows * OUTD;   // 8192*61

    k_he  <<<n_rows / ROWS_HE, 256, 0, stream>>>(spec, W_h, W_e, b_attn, H, E);
    k_attn<<<n_rows / 8,       256, 0, stream>>>(spec, H, E, v_w, W1, b1, pred, a_out);
}